// Round 1
// baseline (456.229 us; speedup 1.0000x reference)
//
#include <hip/hip_runtime.h>
#include <stdint.h>

#define THREADS 256

// Byte-wise dot product: a has 4 bytes in [0,15], m has 4 bytes in {0,1}.
// Returns sum of selected bytes (<= 60).
#if __has_builtin(__builtin_amdgcn_udot4)
__device__ __forceinline__ uint32_t dot4(uint32_t a, uint32_t m) {
  return __builtin_amdgcn_udot4(a, m, 0u, false);
}
#else
__device__ __forceinline__ uint32_t dot4(uint32_t a, uint32_t m) {
  // expand 0x01 bytes to 0xFF bytes (bit0 only is set, so shifts stay in-byte)
  uint32_t mf = m;
  mf |= mf << 1;
  mf |= mf << 2;
  mf |= mf << 4;
  uint32_t t = a & mf;
  uint32_t u = (t & 0xFFFFu) + (t >> 16);   // byte sums <= 30, no carry
  return (u & 0xFFu) + ((u >> 8) & 0xFFu);
}
#endif

// Matches np: clip(round((v - in_min)/rng * 15), 0, 15), round-half-even.
__device__ __forceinline__ float quant1(float v, float in_min, float rng) {
  float t = (v - in_min) / rng * 15.0f;  // IEEE fp32 div (no fast-math)
  t = rintf(t);                          // v_rndne_f32 == np.round
  t = fmaxf(t, 0.0f);
  t = fminf(t, 15.0f);
  return t;
}

__device__ __forceinline__ uint32_t quant4(float4 v, float in_min, float rng) {
  uint32_t a = (uint32_t)quant1(v.x, in_min, rng);
  uint32_t b = (uint32_t)quant1(v.y, in_min, rng);
  uint32_t c = (uint32_t)quant1(v.z, in_min, rng);
  uint32_t d = (uint32_t)quant1(v.w, in_min, rng);
  return a | (b << 8) | (c << 16) | (d << 24);
}

__global__ __launch_bounds__(THREADS) void quantlinear_kernel(
    const float* __restrict__ x, const float* __restrict__ weight,
    const float* __restrict__ p_in_max, const float* __restrict__ p_in_min,
    float* __restrict__ out, int rows) {
  // Per-(o,g) byte masks for plus/minus weight planes + per-o bias.
  __shared__ __align__(16) uint32_t sh_mp[32][4];
  __shared__ __align__(16) uint32_t sh_mm[32][4];
  __shared__ float sh_bias[32];

  const float in_max = p_in_max[0];
  const float in_min = p_in_min[0];
  const float rng = in_max - in_min;

  const int t = threadIdx.x;
  if (t < 128) {
    const int o = t >> 2, g = t & 3;
    float4 w4 = ((const float4*)weight)[o * 4 + g];
    uint32_t mp = (w4.x > 0.f ? 1u : 0u) | ((w4.y > 0.f ? 1u : 0u) << 8) |
                  ((w4.z > 0.f ? 1u : 0u) << 16) | ((w4.w > 0.f ? 1u : 0u) << 24);
    uint32_t mm = (w4.x < 0.f ? 1u : 0u) | ((w4.y < 0.f ? 1u : 0u) << 8) |
                  ((w4.z < 0.f ? 1u : 0u) << 16) | ((w4.w < 0.f ? 1u : 0u) << 24);
    sh_mp[o][g] = mp;
    sh_mm[o][g] = mm;
  } else if (t < 160) {
    const int o = t - 128;
    int s = 0;
    for (int i = 0; i < 16; ++i) {
      float w = weight[o * 16 + i];
      s += (w > 0.f) ? 1 : ((w < 0.f) ? -1 : 0);
    }
    // bias[o] = in_min * sum_i sign(w[o,i])  (exact in fp32 here)
    sh_bias[o] = in_min * (float)s;
  }
  __syncthreads();

  const int row = blockIdx.x * THREADS + threadIdx.x;
  if (row >= rows) return;

  const float4* __restrict__ xv = (const float4*)x;
  float4* __restrict__ outv = (float4*)out;

  const size_t rb = (size_t)row * 4;
  float4 xr0 = xv[rb + 0];
  float4 xr1 = xv[rb + 1];
  float4 xr2 = xv[rb + 2];
  float4 xr3 = xv[rb + 3];

  uint32_t Xq[4];
  Xq[0] = quant4(xr0, in_min, rng);
  Xq[1] = quant4(xr1, in_min, rng);
  Xq[2] = quant4(xr2, in_min, rng);
  Xq[3] = quant4(xr3, in_min, rng);

  const float inv15 = 1.0f / 15.0f;
  const size_t ob = (size_t)row * 8;

  for (int oo = 0; oo < 8; ++oo) {
    float resv[4];
#pragma unroll
    for (int j = 0; j < 4; ++j) {
      const int o = oo * 4 + j;
      float S = 0.f;
#pragma unroll
      for (int g = 0; g < 4; ++g) {
        uint32_t yp = dot4(Xq[g], sh_mp[o][g]);
        uint32_t ym = dot4(Xq[g], sh_mm[o][g]);
        // round(yp/15) in [0,4]; clip(-4,4) is automatic since yp<=60.
        // (float)yp*(1/15) rounds identically to yp/15.0f here: nearest tie
        // boundary is >= 1/30 away for all integer yp in [0,60].
        S += rintf((float)yp * inv15);
        S -= rintf((float)ym * inv15);
      }
      resv[j] = S * rng + sh_bias[o];
    }
    float4 st = make_float4(resv[0], resv[1], resv[2], resv[3]);
    outv[ob + oo] = st;
  }
}

extern "C" void kernel_launch(void* const* d_in, const int* in_sizes, int n_in,
                              void* d_out, int out_size, void* d_ws, size_t ws_size,
                              hipStream_t stream) {
  const float* x = (const float*)d_in[0];
  const float* w = (const float*)d_in[1];
  // d_in[2] is `scale` — unused in the forward pass.
  const float* in_max = (const float*)d_in[3];
  const float* in_min = (const float*)d_in[4];
  float* out = (float*)d_out;

  const int rows = in_sizes[0] / 16;           // B
  const int blocks = (rows + THREADS - 1) / THREADS;  // 8192 for B=2^21
  quantlinear_kernel<<<blocks, THREADS, 0, stream>>>(x, w, in_max, in_min, out,
                                                     rows);
}

// Round 2
// 363.890 us; speedup vs baseline: 1.2538x; 1.2538x over previous
//
#include <hip/hip_runtime.h>
#include <stdint.h>

#define THREADS 256

// Byte-wise dot product with accumulator: a has 4 bytes in [0,15],
// m has 4 bytes in {0,1}. Returns c + sum of selected bytes (<= c+60).
#if __has_builtin(__builtin_amdgcn_udot4)
__device__ __forceinline__ uint32_t dot4acc(uint32_t a, uint32_t m, uint32_t c) {
  return __builtin_amdgcn_udot4(a, m, c, false);
}
#else
__device__ __forceinline__ uint32_t dot4acc(uint32_t a, uint32_t m, uint32_t c) {
  uint32_t mf = m;
  mf |= mf << 1;
  mf |= mf << 2;
  mf |= mf << 4;
  uint32_t t = a & mf;
  uint32_t u = (t & 0xFFFFu) + (t >> 16);   // byte sums <= 30, no carry
  return (u & 0xFFu) + ((u >> 8) & 0xFFu) + c;
}
#endif

// Matches np: clip(round((v - in_min)/rng * 15), 0, 15), round-half-even.
// IEEE fp32 div kept — bit-exactness verified in round 1 (absmax = 0).
__device__ __forceinline__ float quant1(float v, float in_min, float rng) {
  float t = (v - in_min) / rng * 15.0f;
  t = rintf(t);                          // v_rndne_f32 == np.round
  t = fmaxf(t, 0.0f);
  t = fminf(t, 15.0f);
  return t;
}

__device__ __forceinline__ uint32_t quant4(float4 v, float in_min, float rng) {
  uint32_t a = (uint32_t)quant1(v.x, in_min, rng);
  uint32_t b = (uint32_t)quant1(v.y, in_min, rng);
  uint32_t c = (uint32_t)quant1(v.z, in_min, rng);
  uint32_t d = (uint32_t)quant1(v.w, in_min, rng);
  return a | (b << 8) | (c << 16) | (d << 24);
}

__global__ __launch_bounds__(THREADS) void quantlinear_kernel(
    const float* __restrict__ x, const float* __restrict__ weight,
    const float* __restrict__ p_in_max, const float* __restrict__ p_in_min,
    float* __restrict__ out, int rows) {
  // Per-o byte masks (g packed into uint4 lanes) + per-o bias.
  __shared__ __align__(16) uint4 sh_mp[32];
  __shared__ __align__(16) uint4 sh_mm[32];
  __shared__ float sh_bias[32];
  // Output staging tile: 256 rows x 8 float4 = 32 KB.
  // Column swizzle (c + row) & 7 keeps both write and read phases at the
  // 8-cycle b128 minimum (each 8-lane cohort covers all 32 banks).
  __shared__ __align__(16) float4 sh_out[THREADS][8];

  const float in_max = p_in_max[0];
  const float in_min = p_in_min[0];
  const float rng = in_max - in_min;

  const int t = threadIdx.x;
  if (t < 128) {
    const int o = t >> 2, g = t & 3;
    float4 w4 = ((const float4*)weight)[o * 4 + g];
    uint32_t mp = (w4.x > 0.f ? 1u : 0u) | ((w4.y > 0.f ? 1u : 0u) << 8) |
                  ((w4.z > 0.f ? 1u : 0u) << 16) | ((w4.w > 0.f ? 1u : 0u) << 24);
    uint32_t mm = (w4.x < 0.f ? 1u : 0u) | ((w4.y < 0.f ? 1u : 0u) << 8) |
                  ((w4.z < 0.f ? 1u : 0u) << 16) | ((w4.w < 0.f ? 1u : 0u) << 24);
    ((uint32_t*)&sh_mp[o])[g] = mp;
    ((uint32_t*)&sh_mm[o])[g] = mm;
  } else if (t < 160) {
    const int o = t - 128;
    int s = 0;
    for (int i = 0; i < 16; ++i) {
      float w = weight[o * 16 + i];
      s += (w > 0.f) ? 1 : ((w < 0.f) ? -1 : 0);
    }
    sh_bias[o] = in_min * (float)s;  // exact in fp32 here
  }
  __syncthreads();

  const int row = blockIdx.x * THREADS + t;
  const bool active = row < rows;

  uint32_t Xq[4] = {0u, 0u, 0u, 0u};
  if (active) {
    const float4* __restrict__ xv = (const float4*)x;
    const size_t rb = (size_t)row * 4;
    float4 xr0 = xv[rb + 0];
    float4 xr1 = xv[rb + 1];
    float4 xr2 = xv[rb + 2];
    float4 xr3 = xv[rb + 3];
    Xq[0] = quant4(xr0, in_min, rng);
    Xq[1] = quant4(xr1, in_min, rng);
    Xq[2] = quant4(xr2, in_min, rng);
    Xq[3] = quant4(xr3, in_min, rng);
  }

  // round(y/15) for integer y in [0,60] == floor((y+7)/15)
  // == ((y+7)*1093) >> 14 (verified at all transitions). The +7 is folded
  // into the dot4 accumulator. clip(-4,4) is automatic (rp, rm in [0,4]).
#pragma unroll
  for (int oo = 0; oo < 8; ++oo) {
    float res[4];
#pragma unroll
    for (int j = 0; j < 4; ++j) {
      const int o = oo * 4 + j;
      const uint4 mp = sh_mp[o];  // wave-uniform broadcast (16 B)
      const uint4 mm = sh_mm[o];
      int acc = 0;
#pragma unroll
      for (int g = 0; g < 4; ++g) {
        uint32_t yp7 = dot4acc(Xq[g], ((const uint32_t*)&mp)[g], 7u);
        uint32_t ym7 = dot4acc(Xq[g], ((const uint32_t*)&mm)[g], 7u);
        acc += (int)((yp7 * 1093u) >> 14);
        acc -= (int)((ym7 * 1093u) >> 14);
      }
      res[j] = fmaf((float)acc, rng, sh_bias[o]);  // exact: all multiples of |rng|
    }
    sh_out[t][(oo + t) & 7] = make_float4(res[0], res[1], res[2], res[3]);
  }
  __syncthreads();

  // Coalesced store phase: lane-consecutive float4s (16 B/lane).
  float4* __restrict__ outv = (float4*)out;
  const size_t gbase = (size_t)blockIdx.x * (THREADS * 8);
  const size_t glim = (size_t)rows * 8;
#pragma unroll
  for (int s = 0; s < 8; ++s) {
    const int i = s * THREADS + t;
    const int r = i >> 3, c = i & 7;
    float4 v = sh_out[r][(c + r) & 7];
    const size_t gi = gbase + (size_t)i;
    if (gi < glim) outv[gi] = v;
  }
}

extern "C" void kernel_launch(void* const* d_in, const int* in_sizes, int n_in,
                              void* d_out, int out_size, void* d_ws, size_t ws_size,
                              hipStream_t stream) {
  const float* x = (const float*)d_in[0];
  const float* w = (const float*)d_in[1];
  // d_in[2] is `scale` — unused in the forward pass.
  const float* in_max = (const float*)d_in[3];
  const float* in_min = (const float*)d_in[4];
  float* out = (float*)d_out;

  const int rows = in_sizes[0] / 16;                  // B
  const int blocks = (rows + THREADS - 1) / THREADS;  // 8192 for B=2^21
  quantlinear_kernel<<<blocks, THREADS, 0, stream>>>(x, w, in_max, in_min, out,
                                                     rows);
}